// Round 9
// baseline (235.903 us; speedup 1.0000x reference)
//
#include <hip/hip_runtime.h>
#include <hip/hip_fp16.h>
#include <math.h>

#define N_NODES 50000
#define N_EDGES 800000
#define BIGV 1000000000.0f
#define NBLK_GEMM 3125  // 50000 / 16 nodes per block
#define CHUNK 1024      // edges per chunk (pass A granularity)
#define NCHUNK 782      // ceil(800000/1024)
#define NCH4 784        // chunk count padded to multiple of 4
#define NBUCKET 1563    // dst>>5 in [0,1562]  (32 nodes per bucket)
#define NBK4 1564       // bucket count padded to multiple of 4
#define BMAX 768        // LDS record capacity per bucket (Poisson(512)+11sigma)
#define OVFSTRIDE 1024  // global spill slots per bucket

typedef _Float16 half8 __attribute__((ext_vector_type(8)));
typedef float floatx4 __attribute__((ext_vector_type(4)));

__device__ __forceinline__ float clampinf(float x) { return isinf(x) ? BIGV : x; }

// lgkm-only workgroup barrier: leaves global stores in flight.
__device__ __forceinline__ void barrier_lgkm_only() {
    __builtin_amdgcn_sched_barrier(0);
    asm volatile("s_waitcnt lgkmcnt(0)" ::: "memory");
    __builtin_amdgcn_s_barrier();
    __builtin_amdgcn_sched_barrier(0);
}

// ---------------------------------------------------------------------------
// k_prep: W pre-cast (fp16 W^T) + bns zero + per-chunk bucket histogram.
// R8 post-mortem: half-block aggregation re-scanned each bucket twice and
// regressed. Fix: FINER SORT — buckets are now dst>>5 (1563 x ~512 edges),
// so each k_bagg block owns exactly its records. countsT[bucket][chunk].
// ---------------------------------------------------------------------------
__global__ __launch_bounds__(256) void k_prep(const float* __restrict__ W,
                                              __half* __restrict__ wt,
                                              float* __restrict__ bns,
                                              const int* __restrict__ dst,
                                              int* __restrict__ countsT)
{
    __shared__ int hist[NBK4];
    const int t = threadIdx.x;
    const int idx = blockIdx.x * 256 + t;
    if (idx < 16384) {
        int n = idx >> 7, k = idx & 127;
        wt[idx] = __float2half(W[k * 128 + n]);
    }
    if (idx < 256) bns[idx] = 0.f;
    for (int i = t; i < NBK4; i += 256) hist[i] = 0;
    __syncthreads();
    const int base = blockIdx.x * CHUNK;
    for (int i = t; i < CHUNK; i += 256) {
        int e = base + i;
        if (e < N_EDGES) atomicAdd(&hist[dst[e] >> 5], 1);   // LDS atomic
    }
    __syncthreads();
    for (int i = t; i < NBK4; i += 256)
        countsT[(size_t)i * NCH4 + blockIdx.x] = hist[i];    // [bucket][chunk]
}

// ---------------------------------------------------------------------------
// k_off: one wave per bucket — exclusive prefix over the 782 chunks via
// 13-pass shfl_up wave-scan; writes cursC[chunk][bucket] + btot[bucket].
// Grid 391 x 4 waves = 1564 waves (last one zeroes padding).
// ---------------------------------------------------------------------------
__global__ __launch_bounds__(256) void k_off(const int* __restrict__ countsT,
                                             int* __restrict__ cursC,
                                             int* __restrict__ btot)
{
    const int wv = (blockIdx.x << 2) + (threadIdx.x >> 6);   // bucket id
    const int l = threadIdx.x & 63;
    if (wv >= NBUCKET) {
        if (l == 0 && wv < NBK4) btot[wv] = 0;
        return;
    }
    const int* row = countsT + (size_t)wv * NCH4;
    int carry = 0;
    #pragma unroll
    for (int p = 0; p < 13; ++p) {                           // 13*64 = 832 >= 782
        const int c = p * 64 + l;
        const int v = (c < NCHUNK) ? row[c] : 0;
        int x = v;
        #pragma unroll
        for (int o = 1; o < 64; o <<= 1) {
            int u = __shfl_up(x, o);
            if (l >= o) x += u;
        }
        if (c < NCHUNK) cursC[(size_t)c * NBK4 + wv] = carry + x - v;
        carry += __shfl(x, 63);
    }
    if (l == 0) btot[wv] = carry;
}

// ---------------------------------------------------------------------------
// K1: z = h @ W + b via MFMA f16, fp16 z out, fused per-node scores.
// ---------------------------------------------------------------------------
__global__ __launch_bounds__(256) void k_gemm(
    const float* __restrict__ h, const __half* __restrict__ wt,
    const float* __restrict__ bias, const float* __restrict__ attn_w,
    __half* __restrict__ zh, float* __restrict__ sv, float* __restrict__ tv)
{
    __shared__ _Float16 hA[16][136];
    __shared__ float spart[4][16], tpart[4][16];

    const int tid = threadIdx.x;
    const int lane = tid & 63;
    const int wv = tid >> 6;          // wave 0..3
    const int l16 = lane & 15;
    const int oct = lane >> 4;
    const int n0 = wv << 5;           // this wave's 32-col strip
    const int node0 = blockIdx.x << 4;

    // stage h tile as fp16 (512 float4; 32 float4 per row)
    {
        const float4* h4 = (const float4*)(h + (size_t)node0 * 128);
        for (int i = tid; i < 512; i += 256) {
            int r = i >> 5, c4 = i & 31;
            float4 v = h4[i];
            union { __half2 h2[2]; uint2 u; } pk;
            pk.h2[0] = __floats2half2_rn(v.x, v.y);
            pk.h2[1] = __floats2half2_rn(v.z, v.w);
            *(uint2*)&hA[r][c4 << 2] = pk.u;
        }
    }

    // B-fragments in registers
    half8 bfrag[4][2];
    #pragma unroll
    for (int kk = 0; kk < 4; ++kk)
        #pragma unroll
        for (int t = 0; t < 2; ++t)
            bfrag[kk][t] = *(const half8*)(wt + (size_t)(n0 + t * 16 + l16) * 128
                                              + kk * 32 + oct * 8);

    const float bv0 = bias[n0 + l16],         bv1 = bias[n0 + 16 + l16];
    const float ws0 = attn_w[n0 + l16],       ws1 = attn_w[n0 + 16 + l16];
    const float wd0 = attn_w[128 + n0 + l16], wd1 = attn_w[128 + n0 + 16 + l16];

    barrier_lgkm_only();   // staging visible; global loads stay in flight

    floatx4 acc0 = {0.f, 0.f, 0.f, 0.f};
    floatx4 acc1 = {0.f, 0.f, 0.f, 0.f};
    #pragma unroll
    for (int kk = 0; kk < 4; ++kk) {
        half8 a = *(const half8*)&hA[l16][(kk << 5) + (oct << 3)];
        acc0 = __builtin_amdgcn_mfma_f32_16x16x32_f16(a, bfrag[kk][0], acc0, 0, 0, 0);
        acc1 = __builtin_amdgcn_mfma_f32_16x16x32_f16(a, bfrag[kk][1], acc1, 0, 0, 0);
    }

    float s_acc[4], t_acc[4];
    #pragma unroll
    for (int r = 0; r < 4; ++r) {
        float z0 = clampinf(acc0[r] + bv0);
        float z1 = clampinf(acc1[r] + bv1);
        const int row = (oct << 2) + r;
        zh[(size_t)(node0 + row) * 128 + n0 + l16]      = __float2half(z0);
        zh[(size_t)(node0 + row) * 128 + n0 + 16 + l16] = __float2half(z1);
        s_acc[r] = z0 * ws0 + z1 * ws1;
        t_acc[r] = z0 * wd0 + z1 * wd1;
    }
    #pragma unroll
    for (int r = 0; r < 4; ++r) {
        #pragma unroll
        for (int o = 1; o < 16; o <<= 1) {
            s_acc[r] += __shfl_xor(s_acc[r], o);
            t_acc[r] += __shfl_xor(t_acc[r], o);
        }
    }
    if (l16 == 0) {
        #pragma unroll
        for (int r = 0; r < 4; ++r) {
            spart[wv][(oct << 2) + r] = s_acc[r];
            tpart[wv][(oct << 2) + r] = t_acc[r];
        }
    }
    barrier_lgkm_only();
    if (tid < 16) {
        sv[node0 + tid] = spart[0][tid] + spart[1][tid] + spart[2][tid] + spart[3][tid];
        tv[node0 + tid] = tpart[0][tid] + tpart[1][tid] + tpart[2][tid] + tpart[3][tid];
    }
}

// ---------------------------------------------------------------------------
// PASS A (k_scat): per 1024-edge chunk, 512 threads. Cursor setup: coalesced
// cursC row (1564 ints) + redundant scan of btot (391 uint4) for bucket
// bases. Then compute final edge payload with coalesced reads and scatter
// 16B records into bucket slices via LDS cursors. Block 0 publishes bbase.
// ---------------------------------------------------------------------------
__global__ __launch_bounds__(512) void k_scat(
    const int* __restrict__ src, const int* __restrict__ dst,
    const float* __restrict__ sigma,
    const float* __restrict__ sv, const float* __restrict__ tv,
    const float* __restrict__ attn_b,
    const int* __restrict__ cursC, const int* __restrict__ btot,
    float4* __restrict__ tmp, int* __restrict__ bbase_g)
{
    __shared__ int cur[NBK4];
    __shared__ int bb[NBK4];
    __shared__ int tsc[512];
    const int t = threadIdx.x;
    const int self = blockIdx.x;

    for (int i = t; i < NBK4; i += 512) cur[i] = cursC[(size_t)self * NBK4 + i];

    uint4 bt = {0u, 0u, 0u, 0u};
    int tsum = 0;
    if (t < NBK4 / 4) {                          // 391 quads
        bt = ((const uint4*)btot)[t];
        tsum = (int)(bt.x + bt.y + bt.z + bt.w);
    }
    tsc[t] = tsum;
    __syncthreads();
    for (int off = 1; off < 512; off <<= 1) {    // inclusive block scan
        int u = (t >= off) ? tsc[t - off] : 0;
        __syncthreads();
        tsc[t] += u;
        __syncthreads();
    }
    if (t < NBK4 / 4) {
        const int v0 = tsc[t] - tsum;            // exclusive
        bb[4*t+0] = v0;
        bb[4*t+1] = v0 + (int)bt.x;
        bb[4*t+2] = v0 + (int)bt.x + (int)bt.y;
        bb[4*t+3] = v0 + (int)bt.x + (int)bt.y + (int)bt.z;
    }
    __syncthreads();
    for (int i = t; i < NBK4; i += 512) cur[i] += bb[i];
    if (self == 0)
        for (int i = t; i < NBK4; i += 512) bbase_g[i] = bb[i];
    __syncthreads();

    const float ab = attn_b[0];
    const int base = self * CHUNK;
    for (int i = t; i < CHUNK; i += 512) {
        int e = base + i;
        if (e < N_EDGES) {
            int s = src[e];
            int d = dst[e];
            float a = sv[s] + tv[d] + ab;
            a = clampinf(a);
            float ev = a > 0.f ? a : 0.01f * a;  // leaky relu
            int pos = atomicAdd(&cur[d >> 5], 1);  // LDS atomic
            float4 rec;
            rec.x = __int_as_float(s);
            rec.y = sigma[e];
            rec.z = ev;
            rec.w = __int_as_float(d);
            tmp[pos] = rec;
        }
    }
}

// ---------------------------------------------------------------------------
// k_bagg: fused bin + softmax-aggregate + BN-partials. One block (512 thr,
// 8 waves) per ~512-edge bucket of 32 nodes; each wave handles 4 nodes.
// Block scans ONLY its own records (finer sort removed R8's redundancy).
// LDS ~12.6KB -> 4 blocks/CU (thread-limit); grid 1563 = ~6 blocks/CU of
// work -> full residency. Gather loop 2x-unrolled (8 edges in flight).
// Also accumulates per-feature sum/sumsq -> partials[bucket][256].
// ---------------------------------------------------------------------------
__global__ __launch_bounds__(512) void k_bagg(
    const float4* __restrict__ tmp, const int* __restrict__ bbase_g,
    const __half* __restrict__ zh, float4* __restrict__ ovf,
    float* __restrict__ out, float* __restrict__ partials)
{
    __shared__ float4 lrec[BMAX];
    __shared__ int hist[32];
    __shared__ int segs[33];
    __shared__ int cur[32];
    __shared__ float bnS[128], bnQ[128];
    const int t = threadIdx.x;
    const int b = blockIdx.x;
    const int s0 = bbase_g[b];
    const int n  = bbase_g[b + 1] - s0;          // bbase_g[1563] == N_EDGES

    if (t < 32) hist[t] = 0;
    if (t < 128) { bnS[t] = 0.f; bnQ[t] = 0.f; }
    __syncthreads();
    // phase 1: histogram of node-within-bucket (own records only)
    const float* tw = (const float*)tmp;
    for (int i = t; i < n; i += 512) {
        int d = __float_as_int(tw[4 * (size_t)(s0 + i) + 3]);
        atomicAdd(&hist[d & 31], 1);             // LDS atomic
    }
    __syncthreads();
    // 32-bin exclusive scan (lanes 0..31 of wave 0)
    if (t < 32) {
        const int hv = hist[t];
        int x = hv;
        #pragma unroll
        for (int o = 1; o < 32; o <<= 1) {
            int u = __shfl_up(x, o);
            if (t >= o) x += u;
        }
        segs[t] = x - hv;
        cur[t]  = x - hv;
        if (t == 31) segs[32] = x;
    }
    __syncthreads();
    // phase 2: place records binned into LDS (global spill if > BMAX)
    for (int i = t; i < n; i += 512) {
        float4 rec = tmp[s0 + i];
        int d = __float_as_int(rec.w);
        int pos = atomicAdd(&cur[d & 31], 1);
        if (pos < BMAX) lrec[pos] = rec;
        else            ovf[(size_t)b * OVFSTRIDE + (pos - BMAX)] = rec;
    }
    __syncthreads();

    // phase 3: aggregation — wave wv handles nodes j = wv, wv+8, wv+16, wv+24
    const int lane = t & 63;
    const int wv = t >> 6;
    const int grp = lane >> 4;
    const int l16 = lane & 15;
    float pS[8] = {0.f,0.f,0.f,0.f,0.f,0.f,0.f,0.f};
    float pQ[8] = {0.f,0.f,0.f,0.f,0.f,0.f,0.f,0.f};

    for (int j = wv; j < 32; j += 8) {
        const int node = (b << 5) + j;
        if (node >= N_NODES) continue;
        const int beg = segs[j];
        const int deg = segs[j + 1] - beg;
        float acc[8] = {0.f,0.f,0.f,0.f,0.f,0.f,0.f,0.f};

        if (deg > 0) {
            if (deg <= 64) {
                int sidx = 0; float sig = 0.f, e = -INFINITY;
                if (lane < deg) {
                    const int off = beg + lane;
                    float4 r = (off < BMAX) ? lrec[off]
                             : ovf[(size_t)b * OVFSTRIDE + (off - BMAX)];
                    sidx = __float_as_int(r.x); sig = r.y; e = r.z;
                }
                float m = e;
                for (int o = 32; o; o >>= 1) m = fmaxf(m, __shfl_xor(m, o));
                float p = (lane < deg) ? __expf(e - m) : 0.f;
                float dn = p, bs = sig;
                for (int o = 32; o; o >>= 1) {
                    dn += __shfl_xor(dn, o);
                    bs += __shfl_xor(bs, o);
                }
                const float coef = p * sig * (1.0f / dn) / (bs + 1e-6f);
                // 2x-unrolled gather: 8 edges in flight per wave
                for (int c = 0; c < deg; c += 8) {
                    const int j0 = c + grp, j1 = c + 4 + grp;
                    const int js0 = (j0 < deg) ? j0 : 0;
                    const int js1 = (j1 < deg) ? j1 : 0;
                    float cf0 = __shfl(coef, js0); int sj0 = __shfl(sidx, js0);
                    float cf1 = __shfl(coef, js1); int sj1 = __shfl(sidx, js1);
                    uint4 raw0, raw1;
                    if (j0 < deg)
                        raw0 = *(const uint4*)(zh + ((size_t)sj0 << 7) + (l16 << 3));
                    if (j1 < deg)
                        raw1 = *(const uint4*)(zh + ((size_t)sj1 << 7) + (l16 << 3));
                    if (j0 < deg) {
                        const __half2* hp = (const __half2*)&raw0;
                        #pragma unroll
                        for (int k = 0; k < 4; ++k) {
                            float2 f = __half22float2(hp[k]);
                            acc[2*k]   = fmaf(cf0, f.x, acc[2*k]);
                            acc[2*k+1] = fmaf(cf0, f.y, acc[2*k+1]);
                        }
                    }
                    if (j1 < deg) {
                        const __half2* hp = (const __half2*)&raw1;
                        #pragma unroll
                        for (int k = 0; k < 4; ++k) {
                            float2 f = __half22float2(hp[k]);
                            acc[2*k]   = fmaf(cf1, f.x, acc[2*k]);
                            acc[2*k+1] = fmaf(cf1, f.y, acc[2*k+1]);
                        }
                    }
                }
            } else {
                // generic path (deg > 64 — absent for this input, kept correct)
                float m = -INFINITY;
                for (int i = lane; i < deg; i += 64) {
                    const int off = beg + i;
                    float4 r = (off < BMAX) ? lrec[off]
                             : ovf[(size_t)b * OVFSTRIDE + (off - BMAX)];
                    m = fmaxf(m, r.z);
                }
                for (int o = 32; o; o >>= 1) m = fmaxf(m, __shfl_xor(m, o));
                float dn = 0.f, bs = 0.f;
                for (int i = lane; i < deg; i += 64) {
                    const int off = beg + i;
                    float4 r = (off < BMAX) ? lrec[off]
                             : ovf[(size_t)b * OVFSTRIDE + (off - BMAX)];
                    dn += __expf(r.z - m); bs += r.y;
                }
                for (int o = 32; o; o >>= 1) {
                    dn += __shfl_xor(dn, o);
                    bs += __shfl_xor(bs, o);
                }
                const float scale = (1.0f / dn) / (bs + 1e-6f);
                for (int c = 0; c < deg; c += 64) {
                    int i = c + lane;
                    int sidx = 0; float coef = 0.f;
                    if (i < deg) {
                        const int off = beg + i;
                        float4 r = (off < BMAX) ? lrec[off]
                                 : ovf[(size_t)b * OVFSTRIDE + (off - BMAX)];
                        sidx = __float_as_int(r.x);
                        coef = __expf(r.z - m) * r.y * scale;
                    }
                    const int cnt2 = min(64, deg - c);
                    for (int jj = 0; jj < cnt2; jj += 4) {
                        const int j4 = jj + grp;
                        const int js = (j4 < cnt2) ? j4 : 0;
                        float cf = __shfl(coef, js);
                        int sj = __shfl(sidx, js);
                        if (j4 < cnt2) {
                            uint4 raw = *(const uint4*)(zh + ((size_t)sj << 7) + (l16 << 3));
                            const __half2* hp = (const __half2*)&raw;
                            #pragma unroll
                            for (int k = 0; k < 4; ++k) {
                                float2 f = __half22float2(hp[k]);
                                acc[2*k]   = fmaf(cf, f.x, acc[2*k]);
                                acc[2*k+1] = fmaf(cf, f.y, acc[2*k+1]);
                            }
                        }
                    }
                }
            }
        }
        // combine 4 groups: feature 8*l16+k lives in lanes {l16,+16,+32,+48}
        #pragma unroll
        for (int k = 0; k < 8; ++k) {
            acc[k] += __shfl_xor(acc[k], 16);
            acc[k] += __shfl_xor(acc[k], 32);
        }
        if (grp == 0) {
            float o[8];
            #pragma unroll
            for (int k = 0; k < 8; ++k) {
                o[k] = clampinf(acc[k]);
                pS[k] += o[k];
                pQ[k] += o[k] * o[k];
            }
            float4 o0, o1;
            o0.x = o[0]; o0.y = o[1]; o0.z = o[2]; o0.w = o[3];
            o1.x = o[4]; o1.y = o[5]; o1.z = o[6]; o1.w = o[7];
            float4* op = (float4*)(out + (size_t)node * 128 + (l16 << 3));
            op[0] = o0; op[1] = o1;
        }
    }
    // flush BN partials: one LDS float-atomic per (wave, feature)
    if (grp == 0) {
        #pragma unroll
        for (int k = 0; k < 8; ++k) {
            atomicAdd(&bnS[(l16 << 3) + k], pS[k]);
            atomicAdd(&bnQ[(l16 << 3) + k], pQ[k]);
        }
    }
    __syncthreads();
    if (t < 128) {
        partials[(size_t)b * 256 + t]       = bnS[t];
        partials[(size_t)b * 256 + 128 + t] = bnQ[t];
    }
}

// ---------------------------------------------------------------------------
// k_bnred: 64 blocks x 256 thr — each sums ~25 partial rows (coalesced) and
// does ONE global float atomicAdd per feature (16K total). bns zeroed by
// k_prep.
// ---------------------------------------------------------------------------
__global__ __launch_bounds__(256) void k_bnred(const float* __restrict__ partials,
                                               float* __restrict__ bns)
{
    const int t = threadIdx.x;
    const int r0 = blockIdx.x * 25;
    const int r1 = min(r0 + 25, NBUCKET);
    float s = 0.f;
    for (int r = r0; r < r1; ++r) s += partials[(size_t)r * 256 + t];
    atomicAdd(&bns[t], s);
}

// ---------------------------------------------------------------------------
// BN apply + ELU: float4-vectorized; per-feature scale/shift in LDS.
// ---------------------------------------------------------------------------
__global__ __launch_bounds__(256) void k_bnapply(float* __restrict__ io,
                                                 const float* __restrict__ sums,
                                                 const float* __restrict__ gamma,
                                                 const float* __restrict__ beta)
{
    __shared__ float sc[128], sh[128];
    const int tid = threadIdx.x;
    if (tid < 128) {
        const float invn = 1.0f / (float)N_NODES;
        float mu = sums[tid] * invn;
        float var = fmaxf(sums[128 + tid] * invn - mu * mu, 0.f);
        float g = gamma[tid] * rsqrtf(var + 1e-5f);
        sc[tid] = g;
        sh[tid] = beta[tid] - mu * g;
    }
    __syncthreads();
    const size_t idx = (size_t)blockIdx.x * 256 + tid;   // float4 index
    const int f4 = ((int)idx & 31) << 2;
    float4 x = ((const float4*)io)[idx];
    float y0 = x.x * sc[f4 + 0] + sh[f4 + 0];
    float y1 = x.y * sc[f4 + 1] + sh[f4 + 1];
    float y2 = x.z * sc[f4 + 2] + sh[f4 + 2];
    float y3 = x.w * sc[f4 + 3] + sh[f4 + 3];
    float4 o;
    o.x = y0 > 0.f ? y0 : expm1f(y0);
    o.y = y1 > 0.f ? y1 : expm1f(y1);
    o.z = y2 > 0.f ? y2 : expm1f(y2);
    o.w = y3 > 0.f ? y3 : expm1f(y3);
    ((float4*)io)[idx] = o;
}

// ---------------------------------------------------------------------------
extern "C" void kernel_launch(void* const* d_in, const int* in_sizes, int n_in,
                              void* d_out, int out_size, void* d_ws, size_t ws_size,
                              hipStream_t stream)
{
    const float* h      = (const float*)d_in[0];
    const int*   src    = (const int*)  d_in[1];
    const int*   dst    = (const int*)  d_in[2];
    const float* sigma  = (const float*)d_in[3];
    const float* fc_w   = (const float*)d_in[4];
    const float* fc_b   = (const float*)d_in[5];
    const float* attn_w = (const float*)d_in[6];
    const float* attn_b = (const float*)d_in[7];
    const float* gamma  = (const float*)d_in[8];
    const float* beta   = (const float*)d_in[9];
    float* out = (float*)d_out;

    // workspace layout (~63 MB)
    float4* tmp    = (float4*)d_ws;                         // 800000 x 16B
    float4* ovf    = tmp + N_EDGES;                         // 1564*1024 x 16B spill
    __half* zh     = (__half*)(ovf + (size_t)NBK4 * OVFSTRIDE); // 50000*128 fp16
    float*  sv     = (float*)(zh + (size_t)N_NODES * 128);  // 50000
    float*  tv     = sv + N_NODES;                          // 50000
    float*  bns    = tv + N_NODES;                          // 256
    float*  parts  = bns + 256;                             // 1564*256
    __half* wt     = (__half*)(parts + (size_t)NBK4 * 256); // 128*128 fp16 (W^T)
    int*    countsT= (int*)(wt + 16384);                    // 1564*784
    int*    cursC  = countsT + (size_t)NBK4 * NCH4;         // 784*1564
    int*    btot   = cursC + (size_t)NCH4 * NBK4;           // 1564
    int*    bbase  = btot + NBK4;                           // 1564

    k_prep    <<<NCHUNK, 256, 0, stream>>>(fc_w, wt, bns, dst, countsT);
    k_off     <<<NBK4 / 4, 256, 0, stream>>>(countsT, cursC, btot);
    k_gemm    <<<NBLK_GEMM, 256, 0, stream>>>(h, wt, fc_b, attn_w, zh, sv, tv);
    k_scat    <<<NCHUNK, 512, 0, stream>>>(src, dst, sigma, sv, tv, attn_b,
                                           cursC, btot, tmp, bbase);
    k_bagg    <<<NBUCKET, 512, 0, stream>>>(tmp, bbase, zh, ovf, out, parts);
    k_bnred   <<<64, 256, 0, stream>>>(parts, bns);
    k_bnapply <<<(N_NODES * 128) / (256 * 4), 256, 0, stream>>>(out, bns, gamma, beta);
}

// Round 10
// 218.137 us; speedup vs baseline: 1.0814x; 1.0814x over previous
//
#include <hip/hip_runtime.h>
#include <hip/hip_fp16.h>
#include <math.h>

#define N_NODES 50000
#define N_EDGES 800000
#define BIGV 1000000000.0f
#define NBLK_GEMM 3125  // 50000 / 16 nodes per block
#define CHUNK 1024      // edges per chunk (pass A granularity)
#define NCHUNK 782      // ceil(800000/1024)
#define NCH4 784        // chunk count padded to multiple of 4
#define NBUCKET 1563    // dst>>5 in [0,1562]  (32 nodes per bucket)
#define NBK4 1564       // bucket count padded to multiple of 4
#define BMAX 768        // LDS record capacity per bucket (Poisson(512)+11sigma)
#define OVFSTRIDE 1024  // global spill slots per bucket
#define NBLK_BN 512     // bnstats partial blocks

typedef _Float16 half8 __attribute__((ext_vector_type(8)));
typedef float floatx4 __attribute__((ext_vector_type(4)));

__device__ __forceinline__ float clampinf(float x) { return isinf(x) ? BIGV : x; }

// lgkm-only workgroup barrier: leaves global stores in flight.
__device__ __forceinline__ void barrier_lgkm_only() {
    __builtin_amdgcn_sched_barrier(0);
    asm volatile("s_waitcnt lgkmcnt(0)" ::: "memory");
    __builtin_amdgcn_s_barrier();
    __builtin_amdgcn_sched_barrier(0);
}

// ---------------------------------------------------------------------------
// k_prep: W pre-cast (fp16 W^T) + bns zero + per-chunk bucket histogram.
// Buckets: dst>>5 (1563 x ~512 edges). countsT[bucket][chunk].
// ---------------------------------------------------------------------------
__global__ __launch_bounds__(256) void k_prep(const float* __restrict__ W,
                                              __half* __restrict__ wt,
                                              float* __restrict__ bns,
                                              const int* __restrict__ dst,
                                              int* __restrict__ countsT)
{
    __shared__ int hist[NBK4];
    const int t = threadIdx.x;
    const int idx = blockIdx.x * 256 + t;
    if (idx < 16384) {
        int n = idx >> 7, k = idx & 127;
        wt[idx] = __float2half(W[k * 128 + n]);
    }
    if (idx < 256) bns[idx] = 0.f;
    for (int i = t; i < NBK4; i += 256) hist[i] = 0;
    __syncthreads();
    const int base = blockIdx.x * CHUNK;
    for (int i = t; i < CHUNK; i += 256) {
        int e = base + i;
        if (e < N_EDGES) atomicAdd(&hist[dst[e] >> 5], 1);   // LDS atomic
    }
    __syncthreads();
    for (int i = t; i < NBK4; i += 256)
        countsT[(size_t)i * NCH4 + blockIdx.x] = hist[i];    // [bucket][chunk]
}

// ---------------------------------------------------------------------------
// k_off: one wave per bucket — exclusive prefix over the 782 chunks via
// 13-pass shfl_up wave-scan; writes cursC[chunk][bucket] + btot[bucket].
// ---------------------------------------------------------------------------
__global__ __launch_bounds__(256) void k_off(const int* __restrict__ countsT,
                                             int* __restrict__ cursC,
                                             int* __restrict__ btot)
{
    const int wv = (blockIdx.x << 2) + (threadIdx.x >> 6);   // bucket id
    const int l = threadIdx.x & 63;
    if (wv >= NBUCKET) {
        if (l == 0 && wv < NBK4) btot[wv] = 0;
        return;
    }
    const int* row = countsT + (size_t)wv * NCH4;
    int carry = 0;
    #pragma unroll
    for (int p = 0; p < 13; ++p) {                           // 13*64 = 832 >= 782
        const int c = p * 64 + l;
        const int v = (c < NCHUNK) ? row[c] : 0;
        int x = v;
        #pragma unroll
        for (int o = 1; o < 64; o <<= 1) {
            int u = __shfl_up(x, o);
            if (l >= o) x += u;
        }
        if (c < NCHUNK) cursC[(size_t)c * NBK4 + wv] = carry + x - v;
        carry += __shfl(x, 63);
    }
    if (l == 0) btot[wv] = carry;
}

// ---------------------------------------------------------------------------
// K1: z = h @ W + b via MFMA f16, fp16 z out, fused per-node scores.
// ---------------------------------------------------------------------------
__global__ __launch_bounds__(256) void k_gemm(
    const float* __restrict__ h, const __half* __restrict__ wt,
    const float* __restrict__ bias, const float* __restrict__ attn_w,
    __half* __restrict__ zh, float* __restrict__ sv, float* __restrict__ tv)
{
    __shared__ _Float16 hA[16][136];
    __shared__ float spart[4][16], tpart[4][16];

    const int tid = threadIdx.x;
    const int lane = tid & 63;
    const int wv = tid >> 6;          // wave 0..3
    const int l16 = lane & 15;
    const int oct = lane >> 4;
    const int n0 = wv << 5;           // this wave's 32-col strip
    const int node0 = blockIdx.x << 4;

    // stage h tile as fp16 (512 float4; 32 float4 per row)
    {
        const float4* h4 = (const float4*)(h + (size_t)node0 * 128);
        for (int i = tid; i < 512; i += 256) {
            int r = i >> 5, c4 = i & 31;
            float4 v = h4[i];
            union { __half2 h2[2]; uint2 u; } pk;
            pk.h2[0] = __floats2half2_rn(v.x, v.y);
            pk.h2[1] = __floats2half2_rn(v.z, v.w);
            *(uint2*)&hA[r][c4 << 2] = pk.u;
        }
    }

    // B-fragments in registers
    half8 bfrag[4][2];
    #pragma unroll
    for (int kk = 0; kk < 4; ++kk)
        #pragma unroll
        for (int t = 0; t < 2; ++t)
            bfrag[kk][t] = *(const half8*)(wt + (size_t)(n0 + t * 16 + l16) * 128
                                              + kk * 32 + oct * 8);

    const float bv0 = bias[n0 + l16],         bv1 = bias[n0 + 16 + l16];
    const float ws0 = attn_w[n0 + l16],       ws1 = attn_w[n0 + 16 + l16];
    const float wd0 = attn_w[128 + n0 + l16], wd1 = attn_w[128 + n0 + 16 + l16];

    barrier_lgkm_only();   // staging visible; global loads stay in flight

    floatx4 acc0 = {0.f, 0.f, 0.f, 0.f};
    floatx4 acc1 = {0.f, 0.f, 0.f, 0.f};
    #pragma unroll
    for (int kk = 0; kk < 4; ++kk) {
        half8 a = *(const half8*)&hA[l16][(kk << 5) + (oct << 3)];
        acc0 = __builtin_amdgcn_mfma_f32_16x16x32_f16(a, bfrag[kk][0], acc0, 0, 0, 0);
        acc1 = __builtin_amdgcn_mfma_f32_16x16x32_f16(a, bfrag[kk][1], acc1, 0, 0, 0);
    }

    float s_acc[4], t_acc[4];
    #pragma unroll
    for (int r = 0; r < 4; ++r) {
        float z0 = clampinf(acc0[r] + bv0);
        float z1 = clampinf(acc1[r] + bv1);
        const int row = (oct << 2) + r;
        zh[(size_t)(node0 + row) * 128 + n0 + l16]      = __float2half(z0);
        zh[(size_t)(node0 + row) * 128 + n0 + 16 + l16] = __float2half(z1);
        s_acc[r] = z0 * ws0 + z1 * ws1;
        t_acc[r] = z0 * wd0 + z1 * wd1;
    }
    #pragma unroll
    for (int r = 0; r < 4; ++r) {
        #pragma unroll
        for (int o = 1; o < 16; o <<= 1) {
            s_acc[r] += __shfl_xor(s_acc[r], o);
            t_acc[r] += __shfl_xor(t_acc[r], o);
        }
    }
    if (l16 == 0) {
        #pragma unroll
        for (int r = 0; r < 4; ++r) {
            spart[wv][(oct << 2) + r] = s_acc[r];
            tpart[wv][(oct << 2) + r] = t_acc[r];
        }
    }
    barrier_lgkm_only();
    if (tid < 16) {
        sv[node0 + tid] = spart[0][tid] + spart[1][tid] + spart[2][tid] + spart[3][tid];
        tv[node0 + tid] = tpart[0][tid] + tpart[1][tid] + tpart[2][tid] + tpart[3][tid];
    }
}

// ---------------------------------------------------------------------------
// PASS A (k_scat): per 1024-edge chunk, 512 threads. Coalesced cursC row +
// redundant btot scan for bucket bases, then scatter final 16B records into
// bucket slices via LDS cursors. Block 0 publishes bbase.
// ---------------------------------------------------------------------------
__global__ __launch_bounds__(512) void k_scat(
    const int* __restrict__ src, const int* __restrict__ dst,
    const float* __restrict__ sigma,
    const float* __restrict__ sv, const float* __restrict__ tv,
    const float* __restrict__ attn_b,
    const int* __restrict__ cursC, const int* __restrict__ btot,
    float4* __restrict__ tmp, int* __restrict__ bbase_g)
{
    __shared__ int cur[NBK4];
    __shared__ int bb[NBK4];
    __shared__ int tsc[512];
    const int t = threadIdx.x;
    const int self = blockIdx.x;

    for (int i = t; i < NBK4; i += 512) cur[i] = cursC[(size_t)self * NBK4 + i];

    uint4 bt = {0u, 0u, 0u, 0u};
    int tsum = 0;
    if (t < NBK4 / 4) {                          // 391 quads
        bt = ((const uint4*)btot)[t];
        tsum = (int)(bt.x + bt.y + bt.z + bt.w);
    }
    tsc[t] = tsum;
    __syncthreads();
    for (int off = 1; off < 512; off <<= 1) {    // inclusive block scan
        int u = (t >= off) ? tsc[t - off] : 0;
        __syncthreads();
        tsc[t] += u;
        __syncthreads();
    }
    if (t < NBK4 / 4) {
        const int v0 = tsc[t] - tsum;            // exclusive
        bb[4*t+0] = v0;
        bb[4*t+1] = v0 + (int)bt.x;
        bb[4*t+2] = v0 + (int)bt.x + (int)bt.y;
        bb[4*t+3] = v0 + (int)bt.x + (int)bt.y + (int)bt.z;
    }
    __syncthreads();
    for (int i = t; i < NBK4; i += 512) cur[i] += bb[i];
    if (self == 0)
        for (int i = t; i < NBK4; i += 512) bbase_g[i] = bb[i];
    __syncthreads();

    const float ab = attn_b[0];
    const int base = self * CHUNK;
    for (int i = t; i < CHUNK; i += 512) {
        int e = base + i;
        if (e < N_EDGES) {
            int s = src[e];
            int d = dst[e];
            float a = sv[s] + tv[d] + ab;
            a = clampinf(a);
            float ev = a > 0.f ? a : 0.01f * a;  // leaky relu
            int pos = atomicAdd(&cur[d >> 5], 1);  // LDS atomic
            float4 rec;
            rec.x = __int_as_float(s);
            rec.y = sigma[e];
            rec.z = ev;
            rec.w = __int_as_float(d);
            tmp[pos] = rec;
        }
    }
}

// ---------------------------------------------------------------------------
// k_bagg: fused bin + softmax-aggregate. One block (512 thr, 8 waves) per
// ~512-edge bucket of 32 nodes; each wave handles 4 nodes.
// R9 post-mortem: R8/R9's rewritten gather (conditional raw0/raw1, +24 VGPR)
// was the regression — same VALU-work, +22us stall. Root limit in ALL
// versions: ~1 gather in flight per wave (shfl->shfl->load chain).
// THIS ROUND: after softmax, coef is written into lrec[edge].y (wave-private
// LDS segment). Gather loop then has NO shfl: each 16-lane group reads
// {srcbits,coef} as an 8B LDS broadcast (address = loop counter only),
// loads are CLAMPED + UNCONDITIONAL (cf=0 nulls OOB), 4x unrolled ->
// 4 independent global loads in flight per wave.
// ---------------------------------------------------------------------------
__global__ __launch_bounds__(512) void k_bagg(
    const float4* __restrict__ tmp, const int* __restrict__ bbase_g,
    const __half* __restrict__ zh, float4* __restrict__ ovf,
    float* __restrict__ out)
{
    __shared__ float4 lrec[BMAX];
    __shared__ int hist[32];
    __shared__ int segs[33];
    __shared__ int cur[32];
    const int t = threadIdx.x;
    const int b = blockIdx.x;
    const int s0 = bbase_g[b];
    const int n  = bbase_g[b + 1] - s0;          // bbase_g[1563] == N_EDGES

    if (t < 32) hist[t] = 0;
    __syncthreads();
    // phase 1: histogram of node-within-bucket
    const float* tw = (const float*)tmp;
    for (int i = t; i < n; i += 512) {
        int d = __float_as_int(tw[4 * (size_t)(s0 + i) + 3]);
        atomicAdd(&hist[d & 31], 1);             // LDS atomic
    }
    __syncthreads();
    // 32-bin exclusive scan (lanes 0..31 of wave 0)
    if (t < 32) {
        const int hv = hist[t];
        int x = hv;
        #pragma unroll
        for (int o = 1; o < 32; o <<= 1) {
            int u = __shfl_up(x, o);
            if (t >= o) x += u;
        }
        segs[t] = x - hv;
        cur[t]  = x - hv;
        if (t == 31) segs[32] = x;
    }
    __syncthreads();
    // phase 2: place records binned into LDS (global spill if > BMAX)
    for (int i = t; i < n; i += 512) {
        float4 rec = tmp[s0 + i];
        int d = __float_as_int(rec.w);
        int pos = atomicAdd(&cur[d & 31], 1);
        if (pos < BMAX) lrec[pos] = rec;
        else            ovf[(size_t)b * OVFSTRIDE + (pos - BMAX)] = rec;
    }
    __syncthreads();

    // phase 3: aggregation — wave wv handles nodes j = wv, wv+8, wv+16, wv+24
    const int lane = t & 63;
    const int wv = t >> 6;
    const int grp = lane >> 4;
    const int l16 = lane & 15;

    for (int j = wv; j < 32; j += 8) {
        const int node = (b << 5) + j;
        if (node >= N_NODES) continue;
        const int beg = segs[j];
        const int deg = segs[j + 1] - beg;
        float acc[8] = {0.f,0.f,0.f,0.f,0.f,0.f,0.f,0.f};

        if (deg > 0) {
            if (deg <= 64 && n <= BMAX) {
                // ---- optimized path: shfl-free, 4 loads in flight ----
                int sidx = 0; float sig = 0.f, e = -INFINITY;
                if (lane < deg) {
                    float4 r = lrec[beg + lane];
                    sidx = __float_as_int(r.x); sig = r.y; e = r.z;
                }
                float m = e;
                for (int o = 32; o; o >>= 1) m = fmaxf(m, __shfl_xor(m, o));
                float p = (lane < deg) ? __expf(e - m) : 0.f;
                float dn = p, bs = sig;
                for (int o = 32; o; o >>= 1) {
                    dn += __shfl_xor(dn, o);
                    bs += __shfl_xor(bs, o);
                }
                const float coef = p * sig * (1.0f / dn) / (bs + 1e-6f);
                // publish coef into this wave's own LDS segment (.y slot)
                if (lane < deg) lrec[beg + lane].y = coef;
                // gather: address chain = counter -> LDS broadcast -> load
                const int dm = deg - 1;
                for (int c = 0; c < deg; c += 16) {
                    const int j0 = c + grp, j1 = j0 + 4, j2 = j0 + 8, j3 = j0 + 12;
                    float2 q0 = *(const float2*)&lrec[beg + min(j0, dm)];
                    float2 q1 = *(const float2*)&lrec[beg + min(j1, dm)];
                    float2 q2 = *(const float2*)&lrec[beg + min(j2, dm)];
                    float2 q3 = *(const float2*)&lrec[beg + min(j3, dm)];
                    uint4 r0 = *(const uint4*)(zh + ((size_t)__float_as_int(q0.x) << 7) + (l16 << 3));
                    uint4 r1 = *(const uint4*)(zh + ((size_t)__float_as_int(q1.x) << 7) + (l16 << 3));
                    uint4 r2 = *(const uint4*)(zh + ((size_t)__float_as_int(q2.x) << 7) + (l16 << 3));
                    uint4 r3 = *(const uint4*)(zh + ((size_t)__float_as_int(q3.x) << 7) + (l16 << 3));
                    const float c0 = (j0 < deg) ? q0.y : 0.f;
                    const float c1 = (j1 < deg) ? q1.y : 0.f;
                    const float c2 = (j2 < deg) ? q2.y : 0.f;
                    const float c3 = (j3 < deg) ? q3.y : 0.f;
                    const __half2* h0 = (const __half2*)&r0;
                    const __half2* h1 = (const __half2*)&r1;
                    const __half2* h2 = (const __half2*)&r2;
                    const __half2* h3 = (const __half2*)&r3;
                    #pragma unroll
                    for (int k = 0; k < 4; ++k) {
                        float2 f0 = __half22float2(h0[k]);
                        float2 f1 = __half22float2(h1[k]);
                        float2 f2 = __half22float2(h2[k]);
                        float2 f3 = __half22float2(h3[k]);
                        acc[2*k]   = fmaf(c0, f0.x, acc[2*k]);
                        acc[2*k+1] = fmaf(c0, f0.y, acc[2*k+1]);
                        acc[2*k]   = fmaf(c1, f1.x, acc[2*k]);
                        acc[2*k+1] = fmaf(c1, f1.y, acc[2*k+1]);
                        acc[2*k]   = fmaf(c2, f2.x, acc[2*k]);
                        acc[2*k+1] = fmaf(c2, f2.y, acc[2*k+1]);
                        acc[2*k]   = fmaf(c3, f3.x, acc[2*k]);
                        acc[2*k+1] = fmaf(c3, f3.y, acc[2*k+1]);
                    }
                }
            } else if (deg <= 64) {
                // ---- spill fallback (n > BMAX; ~impossible): R7 shfl path ----
                int sidx = 0; float sig = 0.f, e = -INFINITY;
                if (lane < deg) {
                    const int off = beg + lane;
                    float4 r = (off < BMAX) ? lrec[off]
                             : ovf[(size_t)b * OVFSTRIDE + (off - BMAX)];
                    sidx = __float_as_int(r.x); sig = r.y; e = r.z;
                }
                float m = e;
                for (int o = 32; o; o >>= 1) m = fmaxf(m, __shfl_xor(m, o));
                float p = (lane < deg) ? __expf(e - m) : 0.f;
                float dn = p, bs = sig;
                for (int o = 32; o; o >>= 1) {
                    dn += __shfl_xor(dn, o);
                    bs += __shfl_xor(bs, o);
                }
                const float coef = p * sig * (1.0f / dn) / (bs + 1e-6f);
                for (int c = 0; c < deg; c += 4) {
                    const int jj = c + grp;
                    const int js = (jj < deg) ? jj : 0;
                    float cf = __shfl(coef, js);
                    int sj = __shfl(sidx, js);
                    if (jj < deg) {
                        uint4 raw = *(const uint4*)(zh + ((size_t)sj << 7) + (l16 << 3));
                        const __half2* hp = (const __half2*)&raw;
                        #pragma unroll
                        for (int k = 0; k < 4; ++k) {
                            float2 f = __half22float2(hp[k]);
                            acc[2*k]   = fmaf(cf, f.x, acc[2*k]);
                            acc[2*k+1] = fmaf(cf, f.y, acc[2*k+1]);
                        }
                    }
                }
            } else {
                // ---- generic path (deg > 64 — absent here, kept correct) ----
                float m = -INFINITY;
                for (int i = lane; i < deg; i += 64) {
                    const int off = beg + i;
                    float4 r = (off < BMAX) ? lrec[off]
                             : ovf[(size_t)b * OVFSTRIDE + (off - BMAX)];
                    m = fmaxf(m, r.z);
                }
                for (int o = 32; o; o >>= 1) m = fmaxf(m, __shfl_xor(m, o));
                float dn = 0.f, bs = 0.f;
                for (int i = lane; i < deg; i += 64) {
                    const int off = beg + i;
                    float4 r = (off < BMAX) ? lrec[off]
                             : ovf[(size_t)b * OVFSTRIDE + (off - BMAX)];
                    dn += __expf(r.z - m); bs += r.y;
                }
                for (int o = 32; o; o >>= 1) {
                    dn += __shfl_xor(dn, o);
                    bs += __shfl_xor(bs, o);
                }
                const float scale = (1.0f / dn) / (bs + 1e-6f);
                for (int c = 0; c < deg; c += 64) {
                    int i = c + lane;
                    int sidx = 0; float coef = 0.f;
                    if (i < deg) {
                        const int off = beg + i;
                        float4 r = (off < BMAX) ? lrec[off]
                                 : ovf[(size_t)b * OVFSTRIDE + (off - BMAX)];
                        sidx = __float_as_int(r.x);
                        coef = __expf(r.z - m) * r.y * scale;
                    }
                    const int cnt2 = min(64, deg - c);
                    for (int jj = 0; jj < cnt2; jj += 4) {
                        const int j4 = jj + grp;
                        const int js = (j4 < cnt2) ? j4 : 0;
                        float cf = __shfl(coef, js);
                        int sj = __shfl(sidx, js);
                        if (j4 < cnt2) {
                            uint4 raw = *(const uint4*)(zh + ((size_t)sj << 7) + (l16 << 3));
                            const __half2* hp = (const __half2*)&raw;
                            #pragma unroll
                            for (int k = 0; k < 4; ++k) {
                                float2 f = __half22float2(hp[k]);
                                acc[2*k]   = fmaf(cf, f.x, acc[2*k]);
                                acc[2*k+1] = fmaf(cf, f.y, acc[2*k+1]);
                            }
                        }
                    }
                }
            }
        }
        // combine 4 groups: feature 8*l16+k lives in lanes {l16,+16,+32,+48}
        #pragma unroll
        for (int k = 0; k < 8; ++k) {
            acc[k] += __shfl_xor(acc[k], 16);
            acc[k] += __shfl_xor(acc[k], 32);
        }
        if (grp == 0) {
            float4 o0, o1;
            o0.x = clampinf(acc[0]); o0.y = clampinf(acc[1]);
            o0.z = clampinf(acc[2]); o0.w = clampinf(acc[3]);
            o1.x = clampinf(acc[4]); o1.y = clampinf(acc[5]);
            o1.z = clampinf(acc[6]); o1.w = clampinf(acc[7]);
            float4* op = (float4*)(out + (size_t)node * 128 + (l16 << 3));
            op[0] = o0; op[1] = o1;
        }
    }
}

// ---------------------------------------------------------------------------
// BN stats (R7-proven): per-block non-atomic partials + 1-block reducer.
// ---------------------------------------------------------------------------
__global__ __launch_bounds__(256) void k_bnstats(const float* __restrict__ hnew,
                                                 float* __restrict__ partials)
{
    const int tid = threadIdx.x;
    const int f4 = (tid & 31) << 2;
    const int rgrp = tid >> 5;           // 0..7
    float4 s = {0.f, 0.f, 0.f, 0.f}, q = {0.f, 0.f, 0.f, 0.f};
    for (int node = blockIdx.x * 8 + rgrp; node < N_NODES; node += NBLK_BN * 8) {
        float4 v = *(const float4*)(hnew + (size_t)node * 128 + f4);
        s.x += v.x; s.y += v.y; s.z += v.z; s.w += v.w;
        q.x += v.x * v.x; q.y += v.y * v.y; q.z += v.z * v.z; q.w += v.w * v.w;
    }
    __shared__ float4 ls[256], lq[256];
    ls[tid] = s; lq[tid] = q;
    __syncthreads();
    for (int off = 128; off >= 32; off >>= 1) {
        if (tid < off) {
            float4 a = ls[tid + off], b = lq[tid + off];
            ls[tid].x += a.x; ls[tid].y += a.y; ls[tid].z += a.z; ls[tid].w += a.w;
            lq[tid].x += b.x; lq[tid].y += b.y; lq[tid].z += b.z; lq[tid].w += b.w;
        }
        __syncthreads();
    }
    if (tid < 32) {
        float* p = partials + (size_t)blockIdx.x * 256;
        *(float4*)(p + f4)       = ls[tid];
        *(float4*)(p + 128 + f4) = lq[tid];
    }
}

__global__ __launch_bounds__(1024) void k_bnred(const float* __restrict__ partials,
                                                float* __restrict__ sums)
{
    __shared__ float red[4][256];
    const int t = threadIdx.x;
    const int f = t & 255;
    const int part = t >> 8;             // 0..3, each covers 128 blocks
    float s = 0.f;
    #pragma unroll 8
    for (int b = part * (NBLK_BN / 4); b < (part + 1) * (NBLK_BN / 4); ++b)
        s += partials[(size_t)b * 256 + f];
    red[part][f] = s;
    __syncthreads();
    if (part == 0)
        sums[f] = red[0][f] + red[1][f] + red[2][f] + red[3][f];
}

// ---------------------------------------------------------------------------
// BN apply + ELU: float4-vectorized; per-feature scale/shift in LDS.
// ---------------------------------------------------------------------------
__global__ __launch_bounds__(256) void k_bnapply(float* __restrict__ io,
                                                 const float* __restrict__ sums,
                                                 const float* __restrict__ gamma,
                                                 const float* __restrict__ beta)
{
    __shared__ float sc[128], sh[128];
    const int tid = threadIdx.x;
    if (tid < 128) {
        const float invn = 1.0f / (float)N_NODES;
        float mu = sums[tid] * invn;
        float var = fmaxf(sums[128 + tid] * invn - mu * mu, 0.f);
        float g = gamma[tid] * rsqrtf(var + 1e-5f);
        sc[tid] = g;
        sh[tid] = beta[tid] - mu * g;
    }
    __syncthreads();
    const size_t idx = (size_t)blockIdx.x * 256 + tid;   // float4 index
    const int f4 = ((int)idx & 31) << 2;
    float4 x = ((const float4*)io)[idx];
    float y0 = x.x * sc[f4 + 0] + sh[f4 + 0];
    float y1 = x.y * sc[f4 + 1] + sh[f4 + 1];
    float y2 = x.z * sc[f4 + 2] + sh[f4 + 2];
    float y3 = x.w * sc[f4 + 3] + sh[f4 + 3];
    float4 o;
    o.x = y0 > 0.f ? y0 : expm1f(y0);
    o.y = y1 > 0.f ? y1 : expm1f(y1);
    o.z = y2 > 0.f ? y2 : expm1f(y2);
    o.w = y3 > 0.f ? y3 : expm1f(y3);
    ((float4*)io)[idx] = o;
}

// ---------------------------------------------------------------------------
extern "C" void kernel_launch(void* const* d_in, const int* in_sizes, int n_in,
                              void* d_out, int out_size, void* d_ws, size_t ws_size,
                              hipStream_t stream)
{
    const float* h      = (const float*)d_in[0];
    const int*   src    = (const int*)  d_in[1];
    const int*   dst    = (const int*)  d_in[2];
    const float* sigma  = (const float*)d_in[3];
    const float* fc_w   = (const float*)d_in[4];
    const float* fc_b   = (const float*)d_in[5];
    const float* attn_w = (const float*)d_in[6];
    const float* attn_b = (const float*)d_in[7];
    const float* gamma  = (const float*)d_in[8];
    const float* beta   = (const float*)d_in[9];
    float* out = (float*)d_out;

    // workspace layout (~63 MB)
    float4* tmp    = (float4*)d_ws;                         // 800000 x 16B
    float4* ovf    = tmp + N_EDGES;                         // 1564*1024 x 16B spill
    __half* zh     = (__half*)(ovf + (size_t)NBK4 * OVFSTRIDE); // 50000*128 fp16
    float*  sv     = (float*)(zh + (size_t)N_NODES * 128);  // 50000
    float*  tv     = sv + N_NODES;                          // 50000
    float*  bns    = tv + N_NODES;                          // 256
    float*  parts  = bns + 256;                             // 512*256
    __half* wt     = (__half*)(parts + (size_t)NBLK_BN * 256); // 128*128 fp16 (W^T)
    int*    countsT= (int*)(wt + 16384);                    // 1564*784
    int*    cursC  = countsT + (size_t)NBK4 * NCH4;         // 784*1564
    int*    btot   = cursC + (size_t)NCH4 * NBK4;           // 1564
    int*    bbase  = btot + NBK4;                           // 1564

    k_prep    <<<NCHUNK, 256, 0, stream>>>(fc_w, wt, bns, dst, countsT);
    k_off     <<<NBK4 / 4, 256, 0, stream>>>(countsT, cursC, btot);
    k_gemm    <<<NBLK_GEMM, 256, 0, stream>>>(h, wt, fc_b, attn_w, zh, sv, tv);
    k_scat    <<<NCHUNK, 512, 0, stream>>>(src, dst, sigma, sv, tv, attn_b,
                                           cursC, btot, tmp, bbase);
    k_bagg    <<<NBUCKET, 512, 0, stream>>>(tmp, bbase, zh, ovf, out);
    k_bnstats <<<NBLK_BN, 256, 0, stream>>>(out, parts);
    k_bnred   <<<1, 1024, 0, stream>>>(parts, bns);
    k_bnapply <<<(N_NODES * 128) / (256 * 4), 256, 0, stream>>>(out, bns, gamma, beta);
}

// Round 11
// 208.613 us; speedup vs baseline: 1.1308x; 1.0457x over previous
//
#include <hip/hip_runtime.h>
#include <hip/hip_fp16.h>
#include <math.h>

#define N_NODES 50000
#define N_EDGES 800000
#define BIGV 1000000000.0f
#define NBLK_GEMM 3125  // 50000 / 16 nodes per block
#define CHUNK 1024      // edges per chunk (pass A granularity)
#define NCHUNK 782      // ceil(800000/1024)
#define NCH4 784        // chunk count padded to multiple of 4
#define NBUCKET 1563    // dst>>5 in [0,1562]  (32 nodes per bucket)
#define NBK4 1564       // bucket count padded to multiple of 4
#define BMAX 768        // LDS record capacity per bucket (Poisson(512)+11sigma)
#define OVFSTRIDE 1024  // global spill slots per bucket
#define NBLK_BN 512     // bnstats partial blocks

typedef _Float16 half8 __attribute__((ext_vector_type(8)));
typedef float floatx4 __attribute__((ext_vector_type(4)));

__device__ __forceinline__ float clampinf(float x) { return isinf(x) ? BIGV : x; }

// monotone float->int key for LDS atomicMax-based segment max (exact semantics)
__device__ __forceinline__ int fkey(float x) {
    int b = __float_as_int(x);
    return (b >= 0) ? b : (b ^ 0x7FFFFFFF);
}
__device__ __forceinline__ float fkey_inv(int k) {
    return __int_as_float((k >= 0) ? k : (k ^ 0x7FFFFFFF));
}

// lgkm-only workgroup barrier: leaves global stores in flight.
__device__ __forceinline__ void barrier_lgkm_only() {
    __builtin_amdgcn_sched_barrier(0);
    asm volatile("s_waitcnt lgkmcnt(0)" ::: "memory");
    __builtin_amdgcn_s_barrier();
    __builtin_amdgcn_sched_barrier(0);
}

// ---------------------------------------------------------------------------
// k_prep: W pre-cast (fp16 W^T) + bns zero + per-chunk bucket histogram.
// Buckets: dst>>5 (1563 x ~512 edges). countsT[bucket][chunk].
// ---------------------------------------------------------------------------
__global__ __launch_bounds__(256) void k_prep(const float* __restrict__ W,
                                              __half* __restrict__ wt,
                                              float* __restrict__ bns,
                                              const int* __restrict__ dst,
                                              int* __restrict__ countsT)
{
    __shared__ int hist[NBK4];
    const int t = threadIdx.x;
    const int idx = blockIdx.x * 256 + t;
    if (idx < 16384) {
        int n = idx >> 7, k = idx & 127;
        wt[idx] = __float2half(W[k * 128 + n]);
    }
    if (idx < 256) bns[idx] = 0.f;
    for (int i = t; i < NBK4; i += 256) hist[i] = 0;
    __syncthreads();
    const int base = blockIdx.x * CHUNK;
    for (int i = t; i < CHUNK; i += 256) {
        int e = base + i;
        if (e < N_EDGES) atomicAdd(&hist[dst[e] >> 5], 1);   // LDS atomic
    }
    __syncthreads();
    for (int i = t; i < NBK4; i += 256)
        countsT[(size_t)i * NCH4 + blockIdx.x] = hist[i];    // [bucket][chunk]
}

// ---------------------------------------------------------------------------
// k_off: one wave per bucket — exclusive prefix over the 782 chunks via
// 13-pass shfl_up wave-scan; writes cursC[chunk][bucket] + btot[bucket].
// ---------------------------------------------------------------------------
__global__ __launch_bounds__(256) void k_off(const int* __restrict__ countsT,
                                             int* __restrict__ cursC,
                                             int* __restrict__ btot)
{
    const int wv = (blockIdx.x << 2) + (threadIdx.x >> 6);   // bucket id
    const int l = threadIdx.x & 63;
    if (wv >= NBUCKET) {
        if (l == 0 && wv < NBK4) btot[wv] = 0;
        return;
    }
    const int* row = countsT + (size_t)wv * NCH4;
    int carry = 0;
    #pragma unroll
    for (int p = 0; p < 13; ++p) {                           // 13*64 = 832 >= 782
        const int c = p * 64 + l;
        const int v = (c < NCHUNK) ? row[c] : 0;
        int x = v;
        #pragma unroll
        for (int o = 1; o < 64; o <<= 1) {
            int u = __shfl_up(x, o);
            if (l >= o) x += u;
        }
        if (c < NCHUNK) cursC[(size_t)c * NBK4 + wv] = carry + x - v;
        carry += __shfl(x, 63);
    }
    if (l == 0) btot[wv] = carry;
}

// ---------------------------------------------------------------------------
// K1: z = h @ W + b via MFMA f16, fp16 z out, fused per-node scores.
// ---------------------------------------------------------------------------
__global__ __launch_bounds__(256) void k_gemm(
    const float* __restrict__ h, const __half* __restrict__ wt,
    const float* __restrict__ bias, const float* __restrict__ attn_w,
    __half* __restrict__ zh, float* __restrict__ sv, float* __restrict__ tv)
{
    __shared__ _Float16 hA[16][136];
    __shared__ float spart[4][16], tpart[4][16];

    const int tid = threadIdx.x;
    const int lane = tid & 63;
    const int wv = tid >> 6;          // wave 0..3
    const int l16 = lane & 15;
    const int oct = lane >> 4;
    const int n0 = wv << 5;           // this wave's 32-col strip
    const int node0 = blockIdx.x << 4;

    // stage h tile as fp16 (512 float4; 32 float4 per row)
    {
        const float4* h4 = (const float4*)(h + (size_t)node0 * 128);
        for (int i = tid; i < 512; i += 256) {
            int r = i >> 5, c4 = i & 31;
            float4 v = h4[i];
            union { __half2 h2[2]; uint2 u; } pk;
            pk.h2[0] = __floats2half2_rn(v.x, v.y);
            pk.h2[1] = __floats2half2_rn(v.z, v.w);
            *(uint2*)&hA[r][c4 << 2] = pk.u;
        }
    }

    // B-fragments in registers
    half8 bfrag[4][2];
    #pragma unroll
    for (int kk = 0; kk < 4; ++kk)
        #pragma unroll
        for (int t = 0; t < 2; ++t)
            bfrag[kk][t] = *(const half8*)(wt + (size_t)(n0 + t * 16 + l16) * 128
                                              + kk * 32 + oct * 8);

    const float bv0 = bias[n0 + l16],         bv1 = bias[n0 + 16 + l16];
    const float ws0 = attn_w[n0 + l16],       ws1 = attn_w[n0 + 16 + l16];
    const float wd0 = attn_w[128 + n0 + l16], wd1 = attn_w[128 + n0 + 16 + l16];

    barrier_lgkm_only();   // staging visible; global loads stay in flight

    floatx4 acc0 = {0.f, 0.f, 0.f, 0.f};
    floatx4 acc1 = {0.f, 0.f, 0.f, 0.f};
    #pragma unroll
    for (int kk = 0; kk < 4; ++kk) {
        half8 a = *(const half8*)&hA[l16][(kk << 5) + (oct << 3)];
        acc0 = __builtin_amdgcn_mfma_f32_16x16x32_f16(a, bfrag[kk][0], acc0, 0, 0, 0);
        acc1 = __builtin_amdgcn_mfma_f32_16x16x32_f16(a, bfrag[kk][1], acc1, 0, 0, 0);
    }

    float s_acc[4], t_acc[4];
    #pragma unroll
    for (int r = 0; r < 4; ++r) {
        float z0 = clampinf(acc0[r] + bv0);
        float z1 = clampinf(acc1[r] + bv1);
        const int row = (oct << 2) + r;
        zh[(size_t)(node0 + row) * 128 + n0 + l16]      = __float2half(z0);
        zh[(size_t)(node0 + row) * 128 + n0 + 16 + l16] = __float2half(z1);
        s_acc[r] = z0 * ws0 + z1 * ws1;
        t_acc[r] = z0 * wd0 + z1 * wd1;
    }
    #pragma unroll
    for (int r = 0; r < 4; ++r) {
        #pragma unroll
        for (int o = 1; o < 16; o <<= 1) {
            s_acc[r] += __shfl_xor(s_acc[r], o);
            t_acc[r] += __shfl_xor(t_acc[r], o);
        }
    }
    if (l16 == 0) {
        #pragma unroll
        for (int r = 0; r < 4; ++r) {
            spart[wv][(oct << 2) + r] = s_acc[r];
            tpart[wv][(oct << 2) + r] = t_acc[r];
        }
    }
    barrier_lgkm_only();
    if (tid < 16) {
        sv[node0 + tid] = spart[0][tid] + spart[1][tid] + spart[2][tid] + spart[3][tid];
        tv[node0 + tid] = tpart[0][tid] + tpart[1][tid] + tpart[2][tid] + tpart[3][tid];
    }
}

// ---------------------------------------------------------------------------
// PASS A (k_scat): per 1024-edge chunk, 512 threads. Coalesced cursC row +
// redundant btot scan for bucket bases, then scatter final 16B records into
// bucket slices via LDS cursors. Block 0 publishes bbase.
// ---------------------------------------------------------------------------
__global__ __launch_bounds__(512) void k_scat(
    const int* __restrict__ src, const int* __restrict__ dst,
    const float* __restrict__ sigma,
    const float* __restrict__ sv, const float* __restrict__ tv,
    const float* __restrict__ attn_b,
    const int* __restrict__ cursC, const int* __restrict__ btot,
    float4* __restrict__ tmp, int* __restrict__ bbase_g)
{
    __shared__ int cur[NBK4];
    __shared__ int bb[NBK4];
    __shared__ int tsc[512];
    const int t = threadIdx.x;
    const int self = blockIdx.x;

    for (int i = t; i < NBK4; i += 512) cur[i] = cursC[(size_t)self * NBK4 + i];

    uint4 bt = {0u, 0u, 0u, 0u};
    int tsum = 0;
    if (t < NBK4 / 4) {                          // 391 quads
        bt = ((const uint4*)btot)[t];
        tsum = (int)(bt.x + bt.y + bt.z + bt.w);
    }
    tsc[t] = tsum;
    __syncthreads();
    for (int off = 1; off < 512; off <<= 1) {    // inclusive block scan
        int u = (t >= off) ? tsc[t - off] : 0;
        __syncthreads();
        tsc[t] += u;
        __syncthreads();
    }
    if (t < NBK4 / 4) {
        const int v0 = tsc[t] - tsum;            // exclusive
        bb[4*t+0] = v0;
        bb[4*t+1] = v0 + (int)bt.x;
        bb[4*t+2] = v0 + (int)bt.x + (int)bt.y;
        bb[4*t+3] = v0 + (int)bt.x + (int)bt.y + (int)bt.z;
    }
    __syncthreads();
    for (int i = t; i < NBK4; i += 512) cur[i] += bb[i];
    if (self == 0)
        for (int i = t; i < NBK4; i += 512) bbase_g[i] = bb[i];
    __syncthreads();

    const float ab = attn_b[0];
    const int base = self * CHUNK;
    for (int i = t; i < CHUNK; i += 512) {
        int e = base + i;
        if (e < N_EDGES) {
            int s = src[e];
            int d = dst[e];
            float a = sv[s] + tv[d] + ab;
            a = clampinf(a);
            float ev = a > 0.f ? a : 0.01f * a;  // leaky relu
            int pos = atomicAdd(&cur[d >> 5], 1);  // LDS atomic
            float4 rec;
            rec.x = __int_as_float(s);
            rec.y = sigma[e];
            rec.z = ev;
            rec.w = __int_as_float(d);
            tmp[pos] = rec;
        }
    }
}

// ---------------------------------------------------------------------------
// k_bagg: fused bin + EDGE-PARALLEL softmax + gather-aggregate.
// R10 post-mortem: two different gather loops both land at ~51.5us -> the
// gather was never the whole story. Remaining chain: per-node wave softmax
// (3 x 6-level shfl reduces, 48/64 lanes idle at deg~16, 4 nodes serialized
// per wave) = Common-mistake #6. THIS ROUND: softmax is edge-parallel via
// LDS atomics — binning also accumulates bsum (atomicAdd) and segment max
// (int-keyed atomicMax, exact semantics); phase 2b computes p=exp(e-m)
// per-edge (all 512 lanes busy), adds to dn, stores p*sigma into .w; phase 3
// is a pure shfl-free 4-deep gather with cf = .w * scale[node]. tmp is read
// once (records held in registers across phases 1-2).
// ---------------------------------------------------------------------------
__global__ __launch_bounds__(512) void k_bagg(
    const float4* __restrict__ tmp, const int* __restrict__ bbase_g,
    const __half* __restrict__ zh, float4* __restrict__ ovf,
    float* __restrict__ out)
{
    __shared__ float4 lrec[BMAX];
    __shared__ int hist[32];
    __shared__ int segs[33];
    __shared__ int cur[32];
    __shared__ int mkey[32];
    __shared__ float dnod[32], bsum[32], scale[32];
    const int t = threadIdx.x;
    const int b = blockIdx.x;
    const int s0 = bbase_g[b];
    const int n  = bbase_g[b + 1] - s0;          // bbase_g[1563] == N_EDGES

    if (t < 32) {
        hist[t] = 0; mkey[t] = (int)0x80000000;
        dnod[t] = 0.f; bsum[t] = 0.f;
    }
    __syncthreads();

    // phase 1: histogram; hold up to 2 records in registers (n <= 1024 at
    // +23 sigma; rare-loop re-reads beyond that, keeping correctness)
    float4 rec0, rec1;
    const bool h0 = (t < n), h1 = (t + 512 < n);
    if (h0) rec0 = tmp[s0 + t];
    if (h1) rec1 = tmp[s0 + t + 512];
    if (h0) atomicAdd(&hist[__float_as_int(rec0.w) & 31], 1);
    if (h1) atomicAdd(&hist[__float_as_int(rec1.w) & 31], 1);
    for (int i = t + 1024; i < n; i += 512)
        atomicAdd(&hist[__float_as_int(tmp[s0 + i].w) & 31], 1);
    __syncthreads();
    // 32-bin exclusive scan (lanes 0..31 of wave 0)
    if (t < 32) {
        const int hv = hist[t];
        int x = hv;
        #pragma unroll
        for (int o = 1; o < 32; o <<= 1) {
            int u = __shfl_up(x, o);
            if (t >= o) x += u;
        }
        segs[t] = x - hv;
        cur[t]  = x - hv;
        if (t == 31) segs[32] = x;
    }
    __syncthreads();
    // phase 2: place records + accumulate bsum + segment max (LDS atomics)
    if (h0) {
        const int bin = __float_as_int(rec0.w) & 31;
        int pos = atomicAdd(&cur[bin], 1);
        if (pos < BMAX) lrec[pos] = rec0;
        else            ovf[(size_t)b * OVFSTRIDE + (pos - BMAX)] = rec0;
        atomicAdd(&bsum[bin], rec0.y);
        atomicMax(&mkey[bin], fkey(rec0.z));
    }
    if (h1) {
        const int bin = __float_as_int(rec1.w) & 31;
        int pos = atomicAdd(&cur[bin], 1);
        if (pos < BMAX) lrec[pos] = rec1;
        else            ovf[(size_t)b * OVFSTRIDE + (pos - BMAX)] = rec1;
        atomicAdd(&bsum[bin], rec1.y);
        atomicMax(&mkey[bin], fkey(rec1.z));
    }
    for (int i = t + 1024; i < n; i += 512) {
        float4 rec = tmp[s0 + i];
        const int bin = __float_as_int(rec.w) & 31;
        int pos = atomicAdd(&cur[bin], 1);
        if (pos < BMAX) lrec[pos] = rec;
        else            ovf[(size_t)b * OVFSTRIDE + (pos - BMAX)] = rec;
        atomicAdd(&bsum[bin], rec.y);
        atomicMax(&mkey[bin], fkey(rec.z));
    }
    __syncthreads();
    // phase 2b (edge-parallel softmax): p = exp(e - m); dn += p; .w = p*sigma
    if (n <= BMAX) {
        for (int i = t; i < n; i += 512) {
            float4 r = lrec[i];
            const int bin = __float_as_int(r.w) & 31;
            const float m = fkey_inv(mkey[bin]);
            const float p = __expf(r.z - m);
            atomicAdd(&dnod[bin], p);
            lrec[i].w = p * r.y;
        }
    }
    __syncthreads();
    if (t < 32) scale[t] = (1.0f / dnod[t]) / (bsum[t] + 1e-6f);
    __syncthreads();

    // phase 3: pure gather — wave wv handles nodes j = wv, wv+8, wv+16, wv+24
    const int lane = t & 63;
    const int wv = t >> 6;
    const int grp = lane >> 4;
    const int l16 = lane & 15;

    for (int j = wv; j < 32; j += 8) {
        const int node = (b << 5) + j;
        if (node >= N_NODES) continue;
        const int beg = segs[j];
        const int deg = segs[j + 1] - beg;
        float acc[8] = {0.f,0.f,0.f,0.f,0.f,0.f,0.f,0.f};

        if (deg > 0) {
            if (n <= BMAX) {
                // ---- optimized path: no softmax here, shfl-free gather,
                //      4 independent loads in flight; works for any deg ----
                const float sc = scale[j];
                const int dm = deg - 1;
                for (int c = 0; c < deg; c += 16) {
                    const int j0 = c + grp, j1 = j0 + 4, j2 = j0 + 8, j3 = j0 + 12;
                    float4 q0 = lrec[beg + min(j0, dm)];
                    float4 q1 = lrec[beg + min(j1, dm)];
                    float4 q2 = lrec[beg + min(j2, dm)];
                    float4 q3 = lrec[beg + min(j3, dm)];
                    uint4 r0 = *(const uint4*)(zh + ((size_t)__float_as_int(q0.x) << 7) + (l16 << 3));
                    uint4 r1 = *(const uint4*)(zh + ((size_t)__float_as_int(q1.x) << 7) + (l16 << 3));
                    uint4 r2 = *(const uint4*)(zh + ((size_t)__float_as_int(q2.x) << 7) + (l16 << 3));
                    uint4 r3 = *(const uint4*)(zh + ((size_t)__float_as_int(q3.x) << 7) + (l16 << 3));
                    const float c0 = (j0 < deg) ? q0.w * sc : 0.f;
                    const float c1 = (j1 < deg) ? q1.w * sc : 0.f;
                    const float c2 = (j2 < deg) ? q2.w * sc : 0.f;
                    const float c3 = (j3 < deg) ? q3.w * sc : 0.f;
                    const __half2* h0p = (const __half2*)&r0;
                    const __half2* h1p = (const __half2*)&r1;
                    const __half2* h2p = (const __half2*)&r2;
                    const __half2* h3p = (const __half2*)&r3;
                    #pragma unroll
                    for (int k = 0; k < 4; ++k) {
                        float2 f0 = __half22float2(h0p[k]);
                        float2 f1 = __half22float2(h1p[k]);
                        float2 f2 = __half22float2(h2p[k]);
                        float2 f3 = __half22float2(h3p[k]);
                        acc[2*k]   = fmaf(c0, f0.x, acc[2*k]);
                        acc[2*k+1] = fmaf(c0, f0.y, acc[2*k+1]);
                        acc[2*k]   = fmaf(c1, f1.x, acc[2*k]);
                        acc[2*k+1] = fmaf(c1, f1.y, acc[2*k+1]);
                        acc[2*k]   = fmaf(c2, f2.x, acc[2*k]);
                        acc[2*k+1] = fmaf(c2, f2.y, acc[2*k+1]);
                        acc[2*k]   = fmaf(c3, f3.x, acc[2*k]);
                        acc[2*k+1] = fmaf(c3, f3.y, acc[2*k+1]);
                    }
                }
            } else if (deg <= 64) {
                // ---- spill fallback (n > BMAX; ~impossible): R7 shfl path.
                //      .y (sigma) / .z (e) intact since phase 2b was skipped.
                int sidx = 0; float sig = 0.f, e = -INFINITY;
                if (lane < deg) {
                    const int off = beg + lane;
                    float4 r = (off < BMAX) ? lrec[off]
                             : ovf[(size_t)b * OVFSTRIDE + (off - BMAX)];
                    sidx = __float_as_int(r.x); sig = r.y; e = r.z;
                }
                float m = e;
                for (int o = 32; o; o >>= 1) m = fmaxf(m, __shfl_xor(m, o));
                float p = (lane < deg) ? __expf(e - m) : 0.f;
                float dn = p, bs = sig;
                for (int o = 32; o; o >>= 1) {
                    dn += __shfl_xor(dn, o);
                    bs += __shfl_xor(bs, o);
                }
                const float coef = p * sig * (1.0f / dn) / (bs + 1e-6f);
                for (int c = 0; c < deg; c += 4) {
                    const int jj = c + grp;
                    const int js = (jj < deg) ? jj : 0;
                    float cf = __shfl(coef, js);
                    int sj = __shfl(sidx, js);
                    if (jj < deg) {
                        uint4 raw = *(const uint4*)(zh + ((size_t)sj << 7) + (l16 << 3));
                        const __half2* hp = (const __half2*)&raw;
                        #pragma unroll
                        for (int k = 0; k < 4; ++k) {
                            float2 f = __half22float2(hp[k]);
                            acc[2*k]   = fmaf(cf, f.x, acc[2*k]);
                            acc[2*k+1] = fmaf(cf, f.y, acc[2*k+1]);
                        }
                    }
                }
            } else {
                // ---- generic spill path (deg > 64 AND n > BMAX) ----
                float m = -INFINITY;
                for (int i = lane; i < deg; i += 64) {
                    const int off = beg + i;
                    float4 r = (off < BMAX) ? lrec[off]
                             : ovf[(size_t)b * OVFSTRIDE + (off - BMAX)];
                    m = fmaxf(m, r.z);
                }
                for (int o = 32; o; o >>= 1) m = fmaxf(m, __shfl_xor(m, o));
                float dn = 0.f, bs = 0.f;
                for (int i = lane; i < deg; i += 64) {
                    const int off = beg + i;
                    float4 r = (off < BMAX) ? lrec[off]
                             : ovf[(size_t)b * OVFSTRIDE + (off - BMAX)];
                    dn += __expf(r.z - m); bs += r.y;
                }
                for (int o = 32; o; o >>= 1) {
                    dn += __shfl_xor(dn, o);
                    bs += __shfl_xor(bs, o);
                }
                const float scl = (1.0f / dn) / (bs + 1e-6f);
                for (int c = 0; c < deg; c += 64) {
                    int i = c + lane;
                    int sidx = 0; float coef = 0.f;
                    if (i < deg) {
                        const int off = beg + i;
                        float4 r = (off < BMAX) ? lrec[off]
                                 : ovf[(size_t)b * OVFSTRIDE + (off - BMAX)];
                        sidx = __float_as_int(r.x);
                        coef = __expf(r.z - m) * r.y * scl;
                    }
                    const int cnt2 = min(64, deg - c);
                    for (int jj = 0; jj < cnt2; jj += 4) {
                        const int j4 = jj + grp;
                        const int js = (j4 < cnt2) ? j4 : 0;
                        float cf = __shfl(coef, js);
                        int sj = __shfl(sidx, js);
                        if (j4 < cnt2) {
                            uint4 raw = *(const uint4*)(zh + ((size_t)sj << 7) + (l16 << 3));
                            const __half2* hp = (const __half2*)&raw;
                            #pragma unroll
                            for (int k = 0; k < 4; ++k) {
                                float2 f = __half22float2(hp[k]);
                                acc[2*k]   = fmaf(cf, f.x, acc[2*k]);
                                acc[2*k+1] = fmaf(cf, f.y, acc[2*k+1]);
                            }
                        }
                    }
                }
            }
        }
        // combine 4 groups: feature 8*l16+k lives in lanes {l16,+16,+32,+48}
        #pragma unroll
        for (int k = 0; k < 8; ++k) {
            acc[k] += __shfl_xor(acc[k], 16);
            acc[k] += __shfl_xor(acc[k], 32);
        }
        if (grp == 0) {
            float4 o0, o1;
            o0.x = clampinf(acc[0]); o0.y = clampinf(acc[1]);
            o0.z = clampinf(acc[2]); o0.w = clampinf(acc[3]);
            o1.x = clampinf(acc[4]); o1.y = clampinf(acc[5]);
            o1.z = clampinf(acc[6]); o1.w = clampinf(acc[7]);
            float4* op = (float4*)(out + (size_t)node * 128 + (l16 << 3));
            op[0] = o0; op[1] = o1;
        }
    }
}

// ---------------------------------------------------------------------------
// BN stats (R7-proven): per-block non-atomic partials + 1-block reducer.
// ---------------------------------------------------------------------------
__global__ __launch_bounds__(256) void k_bnstats(const float* __restrict__ hnew,
                                                 float* __restrict__ partials)
{
    const int tid = threadIdx.x;
    const int f4 = (tid & 31) << 2;
    const int rgrp = tid >> 5;           // 0..7
    float4 s = {0.f, 0.f, 0.f, 0.f}, q = {0.f, 0.f, 0.f, 0.f};
    for (int node = blockIdx.x * 8 + rgrp; node < N_NODES; node += NBLK_BN * 8) {
        float4 v = *(const float4*)(hnew + (size_t)node * 128 + f4);
        s.x += v.x; s.y += v.y; s.z += v.z; s.w += v.w;
        q.x += v.x * v.x; q.y += v.y * v.y; q.z += v.z * v.z; q.w += v.w * v.w;
    }
    __shared__ float4 ls[256], lq[256];
    ls[tid] = s; lq[tid] = q;
    __syncthreads();
    for (int off = 128; off >= 32; off >>= 1) {
        if (tid < off) {
            float4 a = ls[tid + off], b = lq[tid + off];
            ls[tid].x += a.x; ls[tid].y += a.y; ls[tid].z += a.z; ls[tid].w += a.w;
            lq[tid].x += b.x; lq[tid].y += b.y; lq[tid].z += b.z; lq[tid].w += b.w;
        }
        __syncthreads();
    }
    if (tid < 32) {
        float* p = partials + (size_t)blockIdx.x * 256;
        *(float4*)(p + f4)       = ls[tid];
        *(float4*)(p + 128 + f4) = lq[tid];
    }
}

__global__ __launch_bounds__(1024) void k_bnred(const float* __restrict__ partials,
                                                float* __restrict__ sums)
{
    __shared__ float red[4][256];
    const int t = threadIdx.x;
    const int f = t & 255;
    const int part = t >> 8;             // 0..3, each covers 128 blocks
    float s = 0.f;
    #pragma unroll 8
    for (int b = part * (NBLK_BN / 4); b < (part + 1) * (NBLK_BN / 4); ++b)
        s += partials[(size_t)b * 256 + f];
    red[part][f] = s;
    __syncthreads();
    if (part == 0)
        sums[f] = red[0][f] + red[1][f] + red[2][f] + red[3][f];
}

// ---------------------------------------------------------------------------
// BN apply + ELU: float4-vectorized; per-feature scale/shift in LDS.
// ---------------------------------------------------------------------------
__global__ __launch_bounds__(256) void k_bnapply(float* __restrict__ io,
                                                 const float* __restrict__ sums,
                                                 const float* __restrict__ gamma,
                                                 const float* __restrict__ beta)
{
    __shared__ float sc[128], sh[128];
    const int tid = threadIdx.x;
    if (tid < 128) {
        const float invn = 1.0f / (float)N_NODES;
        float mu = sums[tid] * invn;
        float var = fmaxf(sums[128 + tid] * invn - mu * mu, 0.f);
        float g = gamma[tid] * rsqrtf(var + 1e-5f);
        sc[tid] = g;
        sh[tid] = beta[tid] - mu * g;
    }
    __syncthreads();
    const size_t idx = (size_t)blockIdx.x * 256 + tid;   // float4 index
    const int f4 = ((int)idx & 31) << 2;
    float4 x = ((const float4*)io)[idx];
    float y0 = x.x * sc[f4 + 0] + sh[f4 + 0];
    float y1 = x.y * sc[f4 + 1] + sh[f4 + 1];
    float y2 = x.z * sc[f4 + 2] + sh[f4 + 2];
    float y3 = x.w * sc[f4 + 3] + sh[f4 + 3];
    float4 o;
    o.x = y0 > 0.f ? y0 : expm1f(y0);
    o.y = y1 > 0.f ? y1 : expm1f(y1);
    o.z = y2 > 0.f ? y2 : expm1f(y2);
    o.w = y3 > 0.f ? y3 : expm1f(y3);
    ((float4*)io)[idx] = o;
}

// ---------------------------------------------------------------------------
extern "C" void kernel_launch(void* const* d_in, const int* in_sizes, int n_in,
                              void* d_out, int out_size, void* d_ws, size_t ws_size,
                              hipStream_t stream)
{
    const float* h      = (const float*)d_in[0];
    const int*   src    = (const int*)  d_in[1];
    const int*   dst    = (const int*)  d_in[2];
    const float* sigma  = (const float*)d_in[3];
    const float* fc_w   = (const float*)d_in[4];
    const float* fc_b   = (const float*)d_in[5];
    const float* attn_w = (const float*)d_in[6];
    const float* attn_b = (const float*)d_in[7];
    const float* gamma  = (const float*)d_in[8];
    const float* beta   = (const float*)d_in[9];
    float* out = (float*)d_out;

    // workspace layout (~63 MB)
    float4* tmp    = (float4*)d_ws;                         // 800000 x 16B
    float4* ovf    = tmp + N_EDGES;                         // 1564*1024 x 16B spill
    __half* zh     = (__half*)(ovf + (size_t)NBK4 * OVFSTRIDE); // 50000*128 fp16
    float*  sv     = (float*)(zh + (size_t)N_NODES * 128);  // 50000
    float*  tv     = sv + N_NODES;                          // 50000
    float*  bns    = tv + N_NODES;                          // 256
    float*  parts  = bns + 256;                             // 512*256
    __half* wt     = (__half*)(parts + (size_t)NBLK_BN * 256); // 128*128 fp16 (W^T)
    int*    countsT= (int*)(wt + 16384);                    // 1564*784
    int*    cursC  = countsT + (size_t)NBK4 * NCH4;         // 784*1564
    int*    btot   = cursC + (size_t)NCH4 * NBK4;           // 1564
    int*    bbase  = btot + NBK4;                           // 1564

    k_prep    <<<NCHUNK, 256, 0, stream>>>(fc_w, wt, bns, dst, countsT);
    k_off     <<<NBK4 / 4, 256, 0, stream>>>(countsT, cursC, btot);
    k_gemm    <<<NBLK_GEMM, 256, 0, stream>>>(h, wt, fc_b, attn_w, zh, sv, tv);
    k_scat    <<<NCHUNK, 512, 0, stream>>>(src, dst, sigma, sv, tv, attn_b,
                                           cursC, btot, tmp, bbase);
    k_bagg    <<<NBUCKET, 512, 0, stream>>>(tmp, bbase, zh, ovf, out);
    k_bnstats <<<NBLK_BN, 256, 0, stream>>>(out, parts);
    k_bnred   <<<1, 1024, 0, stream>>>(parts, bns);
    k_bnapply <<<(N_NODES * 128) / (256 * 4), 256, 0, stream>>>(out, bns, gamma, beta);
}